// Round 4
// baseline (403.384 us; speedup 1.0000x reference)
//
#include <hip/hip_runtime.h>
#include <math.h>

#define NN 512
#define NC 3

// Radial cutoff envelope e[i][j] = (r<4.5)/r, r=sqrt((i+1)^2+(j+1)^2), i,j in 0..3
__device__ __constant__ float d_env[16] = {
    0.70710678f, 0.44721360f, 0.31622777f, 0.24253563f,
    0.44721360f, 0.35355339f, 0.27735010f, 0.22360680f,
    0.31622777f, 0.27735010f, 0.23570226f, 0.00000000f,
    0.24253563f, 0.22360680f, 0.00000000f, 0.00000000f
};

// p-major sine table: ws[p*4 + j] = sin(pi * p * (j+1) / 511), p in 0..511.
// Serves both axes (n == m == 512): sx = ws4[x], sy = ws4[y].
__global__ __launch_bounds__(256) void sine_table_kernel(float* __restrict__ ws) {
    const int t = blockIdx.x * 256 + threadIdx.x;   // 2048 threads
    const int j = t & 3;
    const int p = t >> 2;
    ws[t] = sinf((float)M_PI * (float)p * (1.0f / 511.0f) * (float)(j + 1));
}

// Async global->LDS, 16 B per lane (dest must be linear: base + lane*16).
#define GLOAD_LDS(g, l)                                                        \
    __builtin_amdgcn_global_load_lds(                                          \
        (const __attribute__((address_space(1))) void*)(g),                    \
        (__attribute__((address_space(3))) void*)(l), 16, 0, 0)

// One block = one (b, 8-row group). Displacements are tiny (std ~0.06 px,
// max ~0.4 px: scale=0.096, std(u)=0.64), so bilinear taps touch rows
// y-1..y+1 only: stage a 10-row x 512 x 3ch band (+-1 halo) in LDS.
// Round-3 post-mortem: DS pipe was critical (7 LDS instr/px ~= 62 us), so
// this version moves the per-pixel sine read out of LDS into registers
// (8 float4 global loads/thread, L1-resident 8 KB table) -> 6 LDS instr/px,
// and shrinks the halo 12->10 rows (20% less staging).
// LDS = 3*10*512*4 = 61440 B -> 2 blocks/CU; one block stages while the
// other computes. Per-pixel in-band test with global-gather fallback keeps
// arbitrary displacements correct.
__global__ __launch_bounds__(512, 4) void diffeo_kernel(
    const float* __restrict__ xin,
    const float* __restrict__ Fx,
    const float* __restrict__ Fy,
    float* __restrict__ out,
    const float* __restrict__ ws,
    float scale)
{
    const int tid = threadIdx.x;
    const int bid = blockIdx.x;
    // XCD-contiguous assignment: 4096 blocks, 8 XCDs, bijective (4096%8==0).
    // Consecutive row-groups (shared halo rows) stay on one XCD's L2.
    const int g  = ((bid & 7) << 9) | (bid >> 3);
    const int b  = g >> 6;                 // wave-uniform
    const int y0 = (g & 63) << 3;          // first output row of this block
    const int lo = y0 - 1;                 // first staged row (may be <0, clamped)

    __shared__ float smem[15360];          // [3][10][512] band
    const float* __restrict__ base = xin + (size_t)b * NC * NN * NN;

    // ---- stage 10-row x 3-ch band: 3840 float4, up to 8 per thread ----
#pragma unroll
    for (int k = 0; k < 8; ++k) {
        const int f = tid + (k << 9);                // float4 index in tile
        if (f < 3840) {
            const int ch  = (f >= 2560) ? 2 : ((f >= 1280) ? 1 : 0);
            const int rem = f - ch * 1280;
            const int srow = rem >> 7;               // staged slot 0..9
            const int seg  = rem & 127;              // float4 within row
            const int row  = min(max(lo + srow, 0), NN - 1);
            GLOAD_LDS(base + ((ch << 18) | (row << 9) | (seg << 2)),
                      smem + (f << 2));
        }
    }

    const int y  = y0 + (tid >> 6);                  // wave-uniform row
    const int xb = tid & 63;

    // ---- sine vectors in registers (L1-resident 8 KB table) ----
    float4 sxr[8];
#pragma unroll
    for (int k = 0; k < 8; ++k)
        sxr[k] = *(const float4*)(ws + ((xb | (k << 6)) << 2));
    const float4 sy = *(const float4*)(ws + (y << 2));    // wave-uniform
    const float syv[4] = { sy.x, sy.y, sy.z, sy.w };

    // fold F*e*sy over j, scale included: cu[i] = scale * sum_j F[b,i,j]*e[i,j]*sy[j]
    const float* fx = Fx + b * 16;
    const float* fy = Fy + b * 16;
    float cu[4], cv[4];
#pragma unroll
    for (int i = 0; i < 4; ++i) {
        float su = 0.0f, sv = 0.0f;
#pragma unroll
        for (int j = 0; j < 4; ++j) {
            const float w = d_env[i * 4 + j] * syv[j];
            su += fx[i * 4 + j] * w;
            sv += fy[i * 4 + j] * w;
        }
        cu[i] = scale * su;
        cv[i] = scale * sv;
    }

    float* __restrict__ obase = out + (size_t)b * NC * NN * NN + (size_t)y * NN;
    const float yr = (float)y;

    __syncthreads();                                 // drains vmcnt + barrier

#pragma unroll 4
    for (int k = 0; k < 8; ++k) {
        const int xx = xb | (k << 6);

        const float4 sx = sxr[k];
        const float du = sx.x * cu[0] + sx.y * cu[1] + sx.z * cu[2] + sx.w * cu[3];
        const float dv = sx.x * cv[0] + sx.y * cv[1] + sx.z * cv[2] + sx.w * cv[3];

        const float xn = fminf(fmaxf((float)xx - du, 0.0f), 511.0f);
        const float yn = fminf(fmaxf(yr - dv, 0.0f), 511.0f);
        // clamp floor to 510 so the +1 tap stays in-row; xv=1 there reproduces
        // the edge value to 1 ulp (only hit where xn clamps to exactly 511.0)
        const int xf = min((int)floorf(xn), NN - 2);
        const int yf = min((int)floorf(yn), NN - 2);
        const float xv = xn - (float)xf;
        const float yv = yn - (float)yf;

        float o0, o1, o2;
        const int srow = yf - lo;                    // staged slot of top tap
        if ((unsigned)srow <= 8u) {                  // rows srow, srow+1 staged
            const float* t0 = smem + ((srow << 9) + xf);
#pragma unroll
            for (int c = 0; c < NC; ++c) {
                const float v00 = t0[c * 5120 + 0];
                const float v01 = t0[c * 5120 + 1];
                const float v10 = t0[c * 5120 + 512];
                const float v11 = t0[c * 5120 + 513];
                const float top = v00 + xv * (v01 - v00);
                const float bot = v10 + xv * (v11 - v10);
                const float r = top + yv * (bot - top);
                if (c == 0) o0 = r; else if (c == 1) o1 = r; else o2 = r;
            }
        } else {
            // Essentially-never large-displacement fallback: global gather.
            const int xc = xf + 1;
            const int yc = yf + 1;
            const int o00 = yf * NN + xf;
            const int o01 = yf * NN + xc;
            const int o10 = yc * NN + xf;
            const int o11 = yc * NN + xc;
#pragma unroll
            for (int c = 0; c < NC; ++c) {
                const float* img = base + c * NN * NN;
                const float v00 = img[o00];
                const float v01 = img[o01];
                const float v10 = img[o10];
                const float v11 = img[o11];
                const float top = v00 + xv * (v01 - v00);
                const float bot = v10 + xv * (v11 - v10);
                const float r = top + yv * (bot - top);
                if (c == 0) o0 = r; else if (c == 1) o1 = r; else o2 = r;
            }
        }

        // nontemporal: output never re-read; don't evict the input from L2/L3.
        __builtin_nontemporal_store(o0, obase + 0 * NN * NN + xx);
        __builtin_nontemporal_store(o1, obase + 1 * NN * NN + xx);
        __builtin_nontemporal_store(o2, obase + 2 * NN * NN + xx);
    }
}

extern "C" void kernel_launch(void* const* d_in, const int* in_sizes, int n_in,
                              void* d_out, int out_size, void* d_ws, size_t ws_size,
                              hipStream_t stream) {
    const float* x  = (const float*)d_in[0];
    const float* Fx = (const float*)d_in[1];
    const float* Fy = (const float*)d_in[2];
    float* out = (float*)d_out;
    float* ws  = (float*)d_ws;   // 8 KB sine table (re-built every call; ws re-poisoned)

    // typ = n * sqrt(pi*log(cut)) / 2 ; scale = sqrt(T/typ^2) * n
    const double typ = 512.0 * sqrt(M_PI * log(4.0)) / 2.0;
    const float scale = (float)(sqrt(0.01 / (typ * typ)) * 512.0);

    sine_table_kernel<<<8, 256, 0, stream>>>(ws);
    diffeo_kernel<<<64 * 64, 512, 0, stream>>>(x, Fx, Fy, out, ws, scale);
}

// Round 5
// 338.442 us; speedup vs baseline: 1.1919x; 1.1919x over previous
//
#include <hip/hip_runtime.h>
#include <math.h>

#define NN 512
#define NC 3

// Radial cutoff envelope e[i][j] = (r<4.5)/r, r=sqrt((i+1)^2+(j+1)^2), i,j in 0..3
__device__ __constant__ float d_env[16] = {
    0.70710678f, 0.44721360f, 0.31622777f, 0.24253563f,
    0.44721360f, 0.35355339f, 0.27735010f, 0.22360680f,
    0.31622777f, 0.27735010f, 0.23570226f, 0.00000000f,
    0.24253563f, 0.22360680f, 0.00000000f, 0.00000000f
};

// p-major sine table: ws[p*4 + j] = sin(pi * p * (j+1) / 511), p in 0..511.
// Serves both axes (n == m == 512): sx = ws4[x], sy = ws4[y].
__global__ __launch_bounds__(256) void sine_table_kernel(float* __restrict__ ws) {
    const int t = blockIdx.x * 256 + threadIdx.x;   // 2048 threads
    const int j = t & 3;
    const int p = t >> 2;
    ws[t] = sinf((float)M_PI * (float)p * (1.0f / 511.0f) * (float)(j + 1));
}

// Async global->LDS, 16 B per lane (dest must be linear: base + lane*16).
#define GLOAD_LDS(g, l)                                                        \
    __builtin_amdgcn_global_load_lds(                                          \
        (const __attribute__((address_space(1))) void*)(g),                    \
        (__attribute__((address_space(3))) void*)(l), 16, 0, 0)

// One block = one (b, 8-row group). Displacements are tiny (std ~0.06 px,
// max ~0.4 px), so bilinear taps touch rows y-1..y+1 only: stage a
// 10-row x 512 x 3ch band (+-1 halo) in LDS; 6 ds_read2_b32 per pixel.
// Round-4 post-mortem: "#pragma unroll 4" left the sxr[] index runtime ->
// 128 B/thread scratch spill (exactly the +256 MiB WRITE_SIZE observed).
// Fix: FULL unroll so every sxr[k] access is compile-time static (rule #20).
// LDS = 3*10*512*4 = 61440 B -> 2 blocks/CU; one block stages while the
// other computes. Per-pixel in-band test with global-gather fallback keeps
// arbitrary displacements correct.
__global__ __launch_bounds__(512, 4) void diffeo_kernel(
    const float* __restrict__ xin,
    const float* __restrict__ Fx,
    const float* __restrict__ Fy,
    float* __restrict__ out,
    const float* __restrict__ ws,
    float scale)
{
    const int tid = threadIdx.x;
    const int bid = blockIdx.x;
    // XCD-contiguous assignment: 4096 blocks, 8 XCDs, bijective (4096%8==0).
    // Consecutive row-groups (shared halo rows) stay on one XCD's L2.
    const int g  = ((bid & 7) << 9) | (bid >> 3);
    const int b  = g >> 6;                 // wave-uniform
    const int y0 = (g & 63) << 3;          // first output row of this block
    const int lo = y0 - 1;                 // first staged row (may be <0, clamped)

    __shared__ float smem[15360];          // [3][10][512] band
    const float* __restrict__ base = xin + (size_t)b * NC * NN * NN;

    // ---- stage 10-row x 3-ch band: 3840 float4, up to 8 per thread ----
#pragma unroll
    for (int k = 0; k < 8; ++k) {
        const int f = tid + (k << 9);                // float4 index in tile
        if (f < 3840) {
            const int ch  = (f >= 2560) ? 2 : ((f >= 1280) ? 1 : 0);
            const int rem = f - ch * 1280;
            const int srow = rem >> 7;               // staged slot 0..9
            const int seg  = rem & 127;              // float4 within row
            const int row  = min(max(lo + srow, 0), NN - 1);
            GLOAD_LDS(base + ((ch << 18) | (row << 9) | (seg << 2)),
                      smem + (f << 2));
        }
    }

    const int y  = y0 + (tid >> 6);                  // wave-uniform row
    const int xb = tid & 63;

    // ---- sine vectors in registers (L1-resident 8 KB table) ----
    // Statically indexed everywhere (full unroll below) -> stays in VGPRs.
    float4 sxr[8];
#pragma unroll
    for (int k = 0; k < 8; ++k)
        sxr[k] = *(const float4*)(ws + ((xb | (k << 6)) << 2));
    const float4 sy = *(const float4*)(ws + (y << 2));    // wave-uniform
    const float syv[4] = { sy.x, sy.y, sy.z, sy.w };

    // fold F*e*sy over j, scale included: cu[i] = scale * sum_j F[b,i,j]*e[i,j]*sy[j]
    const float* fx = Fx + b * 16;
    const float* fy = Fy + b * 16;
    float cu[4], cv[4];
#pragma unroll
    for (int i = 0; i < 4; ++i) {
        float su = 0.0f, sv = 0.0f;
#pragma unroll
        for (int j = 0; j < 4; ++j) {
            const float w = d_env[i * 4 + j] * syv[j];
            su += fx[i * 4 + j] * w;
            sv += fy[i * 4 + j] * w;
        }
        cu[i] = scale * su;
        cv[i] = scale * sv;
    }

    float* __restrict__ obase = out + (size_t)b * NC * NN * NN + (size_t)y * NN;
    const float yr = (float)y;

    __syncthreads();                                 // drains vmcnt + barrier

#pragma unroll
    for (int k = 0; k < 8; ++k) {                    // FULL unroll: k static
        const int xx = xb | (k << 6);

        const float4 sx = sxr[k];
        const float du = sx.x * cu[0] + sx.y * cu[1] + sx.z * cu[2] + sx.w * cu[3];
        const float dv = sx.x * cv[0] + sx.y * cv[1] + sx.z * cv[2] + sx.w * cv[3];

        const float xn = fminf(fmaxf((float)xx - du, 0.0f), 511.0f);
        const float yn = fminf(fmaxf(yr - dv, 0.0f), 511.0f);
        // clamp floor to 510 so the +1 tap stays in-row; xv=1 there reproduces
        // the edge value to 1 ulp (only hit where xn clamps to exactly 511.0)
        const int xf = min((int)floorf(xn), NN - 2);
        const int yf = min((int)floorf(yn), NN - 2);
        const float xv = xn - (float)xf;
        const float yv = yn - (float)yf;

        float o0, o1, o2;
        const int srow = yf - lo;                    // staged slot of top tap
        if ((unsigned)srow <= 8u) {                  // rows srow, srow+1 staged
            const float* t0 = smem + ((srow << 9) + xf);
#pragma unroll
            for (int c = 0; c < NC; ++c) {
                const float v00 = t0[c * 5120 + 0];
                const float v01 = t0[c * 5120 + 1];
                const float v10 = t0[c * 5120 + 512];
                const float v11 = t0[c * 5120 + 513];
                const float top = v00 + xv * (v01 - v00);
                const float bot = v10 + xv * (v11 - v10);
                const float r = top + yv * (bot - top);
                if (c == 0) o0 = r; else if (c == 1) o1 = r; else o2 = r;
            }
        } else {
            // Essentially-never large-displacement fallback: global gather.
            const int xc = xf + 1;
            const int yc = yf + 1;
            const int o00 = yf * NN + xf;
            const int o01 = yf * NN + xc;
            const int o10 = yc * NN + xf;
            const int o11 = yc * NN + xc;
#pragma unroll
            for (int c = 0; c < NC; ++c) {
                const float* img = base + c * NN * NN;
                const float v00 = img[o00];
                const float v01 = img[o01];
                const float v10 = img[o10];
                const float v11 = img[o11];
                const float top = v00 + xv * (v01 - v00);
                const float bot = v10 + xv * (v11 - v10);
                const float r = top + yv * (bot - top);
                if (c == 0) o0 = r; else if (c == 1) o1 = r; else o2 = r;
            }
        }

        // nontemporal: output never re-read; don't evict the input from L2/L3.
        __builtin_nontemporal_store(o0, obase + 0 * NN * NN + xx);
        __builtin_nontemporal_store(o1, obase + 1 * NN * NN + xx);
        __builtin_nontemporal_store(o2, obase + 2 * NN * NN + xx);
    }
}

extern "C" void kernel_launch(void* const* d_in, const int* in_sizes, int n_in,
                              void* d_out, int out_size, void* d_ws, size_t ws_size,
                              hipStream_t stream) {
    const float* x  = (const float*)d_in[0];
    const float* Fx = (const float*)d_in[1];
    const float* Fy = (const float*)d_in[2];
    float* out = (float*)d_out;
    float* ws  = (float*)d_ws;   // 8 KB sine table (re-built every call; ws re-poisoned)

    // typ = n * sqrt(pi*log(cut)) / 2 ; scale = sqrt(T/typ^2) * n
    const double typ = 512.0 * sqrt(M_PI * log(4.0)) / 2.0;
    const float scale = (float)(sqrt(0.01 / (typ * typ)) * 512.0);

    sine_table_kernel<<<8, 256, 0, stream>>>(ws);
    diffeo_kernel<<<64 * 64, 512, 0, stream>>>(x, Fx, Fy, out, ws, scale);
}